// Round 2
// baseline (458.070 us; speedup 1.0000x reference)
//
#include <hip/hip_runtime.h>
#include <hip/hip_bf16.h>

// Problem constants (B=4, C1=64, C_=32, C2=64, H=W=64, N=4096)
#define NB 4
#define HH 64
#define WW 64
#define NN 4096

// ---------------- conv 3x3 (pad 1) + BN + SiLU ----------------
// in: [B][CIN][64][64] fp32, w: [COUT][CIN][3][3] fp32
// out: [B][COUT][64][64] fp32
template <int CIN, int COUT>
__global__ __launch_bounds__(256) void conv3_bn_silu(
    const float* __restrict__ in,
    const float* __restrict__ w,
    const float* __restrict__ bng,
    const float* __restrict__ bnb,
    const float* __restrict__ bnm,
    const float* __restrict__ bnv,
    float* __restrict__ out)
{
    const int tid = threadIdx.x;
    const int h0 = blockIdx.x * 4;     // 16 row-tiles
    const int co = blockIdx.y;         // COUT
    const int b  = blockIdx.z;         // NB

    __shared__ float wsm[CIN * 9];
    __shared__ float xs[6][64];

    for (int idx = tid; idx < CIN * 9; idx += 256)
        wsm[idx] = w[(size_t)co * CIN * 9 + idx];

    const float scale = bng[co] / sqrtf(bnv[co] + 1e-5f);
    const float bias  = bnb[co] - bnm[co] * scale;

    const int wcol = tid & 63;
    const int ty   = tid >> 6;         // 0..3

    float acc = 0.f;
    const float* inb = in + (size_t)b * CIN * (HH * WW);

    for (int ci = 0; ci < CIN; ++ci) {
        __syncthreads();
        for (int idx = tid; idx < 384; idx += 256) {
            int r = idx >> 6, cc = idx & 63;
            int gr = h0 - 1 + r;
            float v = 0.f;
            if ((unsigned)gr < 64u) v = inb[(size_t)ci * (HH * WW) + gr * WW + cc];
            xs[r][cc] = v;
        }
        __syncthreads();
        const float* wp = &wsm[ci * 9];
        #pragma unroll
        for (int dy = 0; dy < 3; ++dy) {
            int lr = ty + dy;
            float v0 = (wcol > 0)  ? xs[lr][wcol - 1] : 0.f;
            float v1 = xs[lr][wcol];
            float v2 = (wcol < 63) ? xs[lr][wcol + 1] : 0.f;
            acc = fmaf(wp[dy * 3 + 0], v0, acc);
            acc = fmaf(wp[dy * 3 + 1], v1, acc);
            acc = fmaf(wp[dy * 3 + 2], v2, acc);
        }
    }
    float pre = acc * scale + bias;
    float r = pre / (1.f + __expf(-pre));   // SiLU
    out[(((size_t)b * COUT + co) * HH + (h0 + ty)) * WW + wcol] = r;
}

// ---------------- q/k/v 1x1 projections ----------------
// y: [B][64][4096] fp32 -> q,k: [B][4096][8], v: [B][4096][64] fp32
__global__ __launch_bounds__(256) void qkv_proj(
    const float* __restrict__ y,
    const float* __restrict__ qw, const float* __restrict__ qb,
    const float* __restrict__ kw, const float* __restrict__ kb,
    const float* __restrict__ vw, const float* __restrict__ vb,
    float* __restrict__ qo, float* __restrict__ ko, float* __restrict__ vo)
{
    __shared__ float W[80][64];
    __shared__ float Bv[80];
    const int tid = threadIdx.x;

    for (int idx = tid; idx < 512; idx += 256)  W[idx >> 6][idx & 63]        = qw[idx];
    for (int idx = tid; idx < 512; idx += 256)  W[8 + (idx >> 6)][idx & 63]  = kw[idx];
    for (int idx = tid; idx < 4096; idx += 256) W[16 + (idx >> 6)][idx & 63] = vw[idx];
    if (tid < 8)       Bv[tid] = qb[tid];
    else if (tid < 16) Bv[tid] = kb[tid - 8];
    else if (tid < 80) Bv[tid] = vb[tid - 16];
    __syncthreads();

    const int blk = blockIdx.x;           // 256 blocks: 4 batch x 64 n-tiles
    const int b  = blk >> 6;
    const int n0 = (blk & 63) * 64;
    const int nl = tid & 63;
    const int og = tid >> 6;              // 0..3, 20 output channels each
    const int n  = n0 + nl;

    float acc[20];
    #pragma unroll
    for (int u = 0; u < 20; ++u) acc[u] = Bv[og * 20 + u];

    const float* yb = y + (size_t)b * 64 * NN + n;
    for (int c = 0; c < 64; ++c) {
        float yv = yb[(size_t)c * NN];
        #pragma unroll
        for (int u = 0; u < 20; ++u) acc[u] = fmaf(W[og * 20 + u][c], yv, acc[u]);
    }

    #pragma unroll
    for (int u = 0; u < 20; ++u) {
        int ch = og * 20 + u;
        if (ch < 8)       qo[((size_t)b * NN + n) * 8 + ch]         = acc[u];
        else if (ch < 16) ko[((size_t)b * NN + n) * 8 + (ch - 8)]   = acc[u];
        else              vo[((size_t)b * NN + n) * 64 + (ch - 16)] = acc[u];
    }
}

// ---------------- flash PAM + epilogue ----------------
// q,k: [B][4096][8], v: [B][4096][64], y: [B][64][4096] fp32; x, out: [B][64][4096] fp32
// out = x + 2*gamma*AttnOut + 2*y, AttnOut[c][n] = sum_m softmax_m(q[n].k[m]) * v[c][m]
__global__ __launch_bounds__(256) void flash_pam(
    const float* __restrict__ q,
    const float* __restrict__ k,
    const float* __restrict__ v,
    const float* __restrict__ y,
    const float* __restrict__ x,
    const float* __restrict__ gamma_p,
    float* __restrict__ out)
{
    __shared__ float Ks[64][8];
    __shared__ float Vs[64][68];
    __shared__ float Ps[64][68];   // P[j][i]; reused as OT[c][n] in epilogue
    __shared__ float mrow[64], lrow[64], arow[64];
    __shared__ float pmax[4][64], psum[4][64];

    const int tid = threadIdx.x;
    const int b  = blockIdx.x >> 6;
    const int n0 = (blockIdx.x & 63) << 6;

    const int si = tid & 63;    // S-phase row
    const int jq = tid >> 6;    // S-phase j-quarter
    const int ig = tid >> 4;    // PV: i-group
    const int cg = tid & 15;    // PV: c-group
    const int i0 = ig * 4, c0 = cg * 4;

    float qr[8];
    {
        const float* qp = q + ((size_t)b * NN + n0 + si) * 8;
        #pragma unroll
        for (int d = 0; d < 8; ++d) qr[d] = qp[d];
    }

    float O[4][4];
    #pragma unroll
    for (int r = 0; r < 4; ++r)
        #pragma unroll
        for (int cc = 0; cc < 4; ++cc) O[r][cc] = 0.f;
    if (tid < 64) { mrow[tid] = -1e30f; lrow[tid] = 0.f; }

    const float* kb_ = k + (size_t)b * NN * 8;
    const float* vb_ = v + (size_t)b * NN * 64;

    for (int kb = 0; kb < 64; ++kb) {
        const int m0 = kb * 64;
        // stage K (512 f) and V (4096 f)
        {
            const float2* ksrc = (const float2*)(kb_ + (size_t)m0 * 8);
            ((float2*)&Ks[0][0])[tid] = ksrc[tid];
            const float* vsrc = vb_ + (size_t)m0 * 64;
            #pragma unroll
            for (int t = 0; t < 4; ++t) {
                int f = (tid + 256 * t) * 4;
                int j = f >> 6, c = f & 63;
                *(float4*)&Vs[j][c] = *(const float4*)&vsrc[f];
            }
        }
        __syncthreads();                     // B1

        // S = Q K^T for this tile (each thread: row si, 16 j's)
        float sv[16];
        float tmax = -1e30f;
        #pragma unroll
        for (int jj = 0; jj < 16; ++jj) {
            int j = jq * 16 + jj;
            float s = 0.f;
            #pragma unroll
            for (int d = 0; d < 8; ++d) s = fmaf(qr[d], Ks[j][d], s);
            sv[jj] = s;
            tmax = fmaxf(tmax, s);
        }
        pmax[jq][si] = tmax;
        __syncthreads();                     // B2

        if (tid < 64) {
            float mo = mrow[tid];
            float mn = fmaxf(fmaxf(pmax[0][tid], pmax[1][tid]),
                             fmaxf(pmax[2][tid], pmax[3][tid]));
            mn = fmaxf(mo, mn);
            float a = __expf(mo - mn);
            mrow[tid] = mn; arow[tid] = a; lrow[tid] *= a;
        }
        __syncthreads();                     // B3

        {
            float mi = mrow[si];
            float tsum = 0.f;
            #pragma unroll
            for (int jj = 0; jj < 16; ++jj) {
                int j = jq * 16 + jj;
                float p = __expf(sv[jj] - mi);
                Ps[j][si] = p;
                tsum += p;
            }
            psum[jq][si] = tsum;
        }
        __syncthreads();                     // B4

        if (tid < 64)
            lrow[tid] += psum[0][tid] + psum[1][tid] + psum[2][tid] + psum[3][tid];

        // O = O*alpha + P V  (4x4 register tile per thread)
        {
            float a0 = arow[i0 + 0], a1 = arow[i0 + 1], a2 = arow[i0 + 2], a3 = arow[i0 + 3];
            #pragma unroll
            for (int cc = 0; cc < 4; ++cc) {
                O[0][cc] *= a0; O[1][cc] *= a1; O[2][cc] *= a2; O[3][cc] *= a3;
            }
            #pragma unroll 4
            for (int j = 0; j < 64; ++j) {
                float4 vvv = *(float4*)&Vs[j][c0];
                float4 ppp = *(float4*)&Ps[j][i0];
                O[0][0] = fmaf(ppp.x, vvv.x, O[0][0]);
                O[0][1] = fmaf(ppp.x, vvv.y, O[0][1]);
                O[0][2] = fmaf(ppp.x, vvv.z, O[0][2]);
                O[0][3] = fmaf(ppp.x, vvv.w, O[0][3]);
                O[1][0] = fmaf(ppp.y, vvv.x, O[1][0]);
                O[1][1] = fmaf(ppp.y, vvv.y, O[1][1]);
                O[1][2] = fmaf(ppp.y, vvv.z, O[1][2]);
                O[1][3] = fmaf(ppp.y, vvv.w, O[1][3]);
                O[2][0] = fmaf(ppp.z, vvv.x, O[2][0]);
                O[2][1] = fmaf(ppp.z, vvv.y, O[2][1]);
                O[2][2] = fmaf(ppp.z, vvv.z, O[2][2]);
                O[2][3] = fmaf(ppp.z, vvv.w, O[2][3]);
                O[3][0] = fmaf(ppp.w, vvv.x, O[3][0]);
                O[3][1] = fmaf(ppp.w, vvv.y, O[3][1]);
                O[3][2] = fmaf(ppp.w, vvv.z, O[3][2]);
                O[3][3] = fmaf(ppp.w, vvv.w, O[3][3]);
            }
        }
        __syncthreads();                     // B5
    }

    // epilogue: normalize, transpose via LDS, fuse residuals, store fp32
    const float g2 = 2.f * gamma_p[0];
    #pragma unroll
    for (int r = 0; r < 4; ++r) {
        float inv = 1.f / lrow[i0 + r];
        #pragma unroll
        for (int cc = 0; cc < 4; ++cc)
            Ps[c0 + cc][i0 + r] = O[r][cc] * inv;   // OT[c][n_local]
    }
    __syncthreads();

    const int nn = tid & 63, cq = tid >> 6;
    const size_t base = (size_t)b * 64 * NN + n0 + nn;
    #pragma unroll
    for (int cc = 0; cc < 16; ++cc) {
        int c = cq * 16 + cc;
        float oval = Ps[c][nn];
        size_t idx = base + (size_t)c * NN;
        out[idx] = x[idx] + 2.f * y[idx] + g2 * oval;
    }
}

extern "C" void kernel_launch(void* const* d_in, const int* in_sizes, int n_in,
                              void* d_out, int out_size, void* d_ws, size_t ws_size,
                              hipStream_t stream) {
    const float* x    = (const float*)d_in[0];
    const float* w1   = (const float*)d_in[1];
    const float* g1   = (const float*)d_in[2];
    const float* b1   = (const float*)d_in[3];
    const float* m1   = (const float*)d_in[4];
    const float* v1   = (const float*)d_in[5];
    const float* w2   = (const float*)d_in[6];
    const float* g2   = (const float*)d_in[7];
    const float* b2   = (const float*)d_in[8];
    const float* m2   = (const float*)d_in[9];
    const float* v2   = (const float*)d_in[10];
    const float* qw   = (const float*)d_in[11];
    const float* qb   = (const float*)d_in[12];
    const float* kw   = (const float*)d_in[13];
    const float* kb   = (const float*)d_in[14];
    const float* vw   = (const float*)d_in[15];
    const float* vb   = (const float*)d_in[16];
    const float* gam  = (const float*)d_in[17];
    float* outp = (float*)d_out;

    float* ws = (float*)d_ws;
    float* y1 = ws;                        // 4*32*4096   = 524288
    float* y  = ws + 524288;               // 4*64*4096   = 1048576
    float* qq = ws + 1572864;              // 4*4096*8    = 131072
    float* kk = ws + 1703936;              // 4*4096*8    = 131072
    float* vv = ws + 1835008;              // 4*4096*64   = 1048576  (total 11.5 MB)

    conv3_bn_silu<64, 32><<<dim3(16, 32, NB), 256, 0, stream>>>(
        x, w1, g1, b1, m1, v1, y1);
    conv3_bn_silu<32, 64><<<dim3(16, 64, NB), 256, 0, stream>>>(
        y1, w2, g2, b2, m2, v2, y);
    qkv_proj<<<256, 256, 0, stream>>>(y, qw, qb, kw, kb, vw, vb, qq, kk, vv);
    flash_pam<<<256, 256, 0, stream>>>(qq, kk, vv, y, x, gam, outp);
}

// Round 3
// 263.422 us; speedup vs baseline: 1.7389x; 1.7389x over previous
//
#include <hip/hip_runtime.h>
#include <hip/hip_bf16.h>

#define NB 4
#define NN 4096
#define QT 32

typedef short  bf16x8 __attribute__((ext_vector_type(8)));
typedef float  f32x4  __attribute__((ext_vector_type(4)));

static __device__ __forceinline__ ushort f2bf(float f) {
    unsigned u = __float_as_uint(f);
    u += 0x7fffu + ((u >> 16) & 1u);          // RNE
    return (ushort)(u >> 16);
}

// ---------------- conv 3x3 (pad 1) + BN + SiLU, barrier-free ----------------
// in: [B][CIN][64][64] fp32, w: [COUT][CIN][3][3] fp32 -> out fp32
template <int CIN, int COUT, int CO_G>
__global__ __launch_bounds__(256) void conv3_bn_silu(
    const float* __restrict__ in,
    const float* __restrict__ w,
    const float* __restrict__ bng,
    const float* __restrict__ bnb,
    const float* __restrict__ bnm,
    const float* __restrict__ bnv,
    float* __restrict__ out)
{
    const int tid = threadIdx.x;
    const int r = tid >> 6, c = tid & 63;
    const int h  = blockIdx.x * 4 + r;
    const int co0 = blockIdx.y * CO_G;
    const int b  = blockIdx.z;

    int off[9]; float msk[9];
    #pragma unroll
    for (int dy = -1; dy <= 1; ++dy) {
        #pragma unroll
        for (int dx = -1; dx <= 1; ++dx) {
            int t = (dy + 1) * 3 + (dx + 1);
            int hh = h + dy, cx = c + dx;
            bool v = ((unsigned)hh < 64u) && ((unsigned)cx < 64u);
            int hc = min(max(hh, 0), 63), cc2 = min(max(cx, 0), 63);
            off[t] = hc * 64 + cc2;
            msk[t] = v ? 1.f : 0.f;
        }
    }

    float acc[CO_G];
    #pragma unroll
    for (int u = 0; u < CO_G; ++u) acc[u] = 0.f;

    const float* inb = in + (size_t)b * CIN * 4096;
    const float* wb  = w + (size_t)co0 * CIN * 9;

    for (int ci = 0; ci < CIN; ++ci) {
        float xv[9];
        const float* ip = inb + (size_t)ci * 4096;
        #pragma unroll
        for (int t = 0; t < 9; ++t) xv[t] = ip[off[t]] * msk[t];
        #pragma unroll
        for (int u = 0; u < CO_G; ++u) {
            const float* wp = wb + ((size_t)u * CIN + ci) * 9;   // block-uniform -> s_load
            #pragma unroll
            for (int t = 0; t < 9; ++t)
                acc[u] = fmaf(wp[t], xv[t], acc[u]);
        }
    }

    #pragma unroll
    for (int u = 0; u < CO_G; ++u) {
        int co = co0 + u;
        float scale = bng[co] / sqrtf(bnv[co] + 1e-5f);
        float bias  = bnb[co] - bnm[co] * scale;
        float pre = acc[u] * scale + bias;
        float res = pre / (1.f + __expf(-pre));
        out[(((size_t)b * COUT + co) * 64 + h) * 64 + c] = res;
    }
}

// ---------------- q/k/v 1x1 projections ----------------
// y: [B][64][4096] fp32 -> q,k: [B][4096][8] fp32, vt: [B][64][4096] bf16 (transposed!)
__global__ __launch_bounds__(256) void qkv_proj(
    const float* __restrict__ y,
    const float* __restrict__ qw, const float* __restrict__ qb,
    const float* __restrict__ kw, const float* __restrict__ kb,
    const float* __restrict__ vw, const float* __restrict__ vb,
    float* __restrict__ qo, float* __restrict__ ko, ushort* __restrict__ vt)
{
    __shared__ float W[80][64];
    __shared__ float Bv[80];
    const int tid = threadIdx.x;

    for (int idx = tid; idx < 512; idx += 256)  W[idx >> 6][idx & 63]        = qw[idx];
    for (int idx = tid; idx < 512; idx += 256)  W[8 + (idx >> 6)][idx & 63]  = kw[idx];
    for (int idx = tid; idx < 4096; idx += 256) W[16 + (idx >> 6)][idx & 63] = vw[idx];
    if (tid < 8)       Bv[tid] = qb[tid];
    else if (tid < 16) Bv[tid] = kb[tid - 8];
    else if (tid < 80) Bv[tid] = vb[tid - 16];
    __syncthreads();

    const int blk = blockIdx.x;           // 512 blocks: b = blk>>7, 128 n-tiles of 32
    const int b  = blk >> 7;
    const int n0 = (blk & 127) * 32;
    const int nl = tid & 31;
    const int og = tid >> 5;              // 0..7, 10 output channels each
    const int n  = n0 + nl;

    float acc[10];
    #pragma unroll
    for (int u = 0; u < 10; ++u) acc[u] = Bv[og * 10 + u];

    const float* yb = y + (size_t)b * 64 * NN + n;
    for (int cc = 0; cc < 64; ++cc) {
        float yv = yb[(size_t)cc * NN];
        #pragma unroll
        for (int u = 0; u < 10; ++u) acc[u] = fmaf(W[og * 10 + u][cc], yv, acc[u]);
    }

    #pragma unroll
    for (int u = 0; u < 10; ++u) {
        int ch = og * 10 + u;
        if (ch < 8)       qo[((size_t)b * NN + n) * 8 + ch]       = acc[u];
        else if (ch < 16) ko[((size_t)b * NN + n) * 8 + (ch - 8)] = acc[u];
        else              vt[((size_t)b * 64 + (ch - 16)) * NN + n] = f2bf(acc[u]);
    }
}

// ---------------- flash PAM with MFMA PV + fused epilogue ----------------
// q,k: [B][4096][8] fp32, vt: [B][64][4096] bf16, y: [B][64][4096] fp32
// x, out: [B][64][4096] fp32.  out = x + 2*y + 2*gamma*AttnOut
__global__ __launch_bounds__(256) void flash_pam(
    const float* __restrict__ q,
    const float* __restrict__ k,
    const ushort* __restrict__ vt,
    const float* __restrict__ y,
    const float* __restrict__ x,
    const float* __restrict__ gamma_p,
    float* __restrict__ out)
{
    __shared__ __align__(16) float Ks[64][8];                  // K tile fp32
    __shared__ __align__(16) ushort VtPs[64 * 72 + 32 * 72];   // Vt (c-major) + P, bf16, stride 72
    __shared__ __align__(16) float mrow[32], lrow[32], arow[32];
    __shared__ float pmax[8][32], psum[8][32];

    ushort* Vt = VtPs;               // Vt[c][m], 64 rows, stride 72
    ushort* Pp = VtPs + 64 * 72;     // P[n][m],  32 rows, stride 72
    float*  Ot = (float*)VtPs;       // epilogue reuse: Ot[c][n], stride 36

    const int tid = threadIdx.x;
    const int b  = blockIdx.x >> 7;
    const int n0 = (blockIdx.x & 127) * QT;

    const int si = tid & 31;         // S-phase query row
    const int jq = tid >> 5;         // S-phase j-octet (0..7)

    const int lane = tid & 63;
    const int w    = tid >> 6;
    const int quad = lane >> 4;
    const int l15  = lane & 15;
    const int nsub = w & 1;          // which 16-row n-subtile this wave owns
    const int cpair = w >> 1;        // which pair of 16-col c-subtiles
    const int nloc = nsub * 16 + quad * 4;   // C-layout row base

    // Q row in registers
    f32x4 qa, qb_;
    {
        const float* qp = q + ((size_t)b * NN + n0 + si) * 8;
        qa  = *(const f32x4*)qp;
        qb_ = *(const f32x4*)(qp + 4);
    }

    f32x4 acc[2] = {{0.f, 0.f, 0.f, 0.f}, {0.f, 0.f, 0.f, 0.f}};
    if (tid < 32) { mrow[tid] = -1e30f; lrow[tid] = 0.f; }

    const float*  kg = k  + (size_t)b * NN * 8;
    const ushort* vg = vt + (size_t)b * 64 * NN;

    for (int kb = 0; kb < 64; ++kb) {
        const int m0 = kb * 64;
        // ---- stage K (fp32) and V^T (bf16) ----
        ((float2*)Ks)[tid] = ((const float2*)(kg + (size_t)m0 * 8))[tid];
        {
            const int c = tid >> 2, mc = (tid & 3) * 16;
            const ushort* src = vg + (size_t)c * NN + m0 + mc;
            *(uint4*)&Vt[c * 72 + mc]     = *(const uint4*)src;
            *(uint4*)&Vt[c * 72 + mc + 8] = *(const uint4*)(src + 8);
        }
        __syncthreads();                       // B1

        // ---- S = Q K^T (VALU, K=8) ----
        float sv[8];
        float tmax = -1e30f;
        #pragma unroll
        for (int jj = 0; jj < 8; ++jj) {
            int j = jq * 8 + jj;
            f32x4 k0v = *(const f32x4*)&Ks[j][0];
            f32x4 k1v = *(const f32x4*)&Ks[j][4];
            float s = qa[0]*k0v[0] + qa[1]*k0v[1] + qa[2]*k0v[2] + qa[3]*k0v[3]
                    + qb_[0]*k1v[0] + qb_[1]*k1v[1] + qb_[2]*k1v[2] + qb_[3]*k1v[3];
            sv[jj] = s;
            tmax = fmaxf(tmax, s);
        }
        pmax[jq][si] = tmax;
        __syncthreads();                       // B2

        if (tid < 32) {
            float mo = mrow[tid];
            float mn = mo;
            #pragma unroll
            for (int t = 0; t < 8; ++t) mn = fmaxf(mn, pmax[t][tid]);
            float a = __expf(mo - mn);
            mrow[tid] = mn; arow[tid] = a; lrow[tid] *= a;
        }
        __syncthreads();                       // B3

        // ---- exp + pack P to bf16 in MFMA-A layout (row n, contiguous k) ----
        {
            float mi = mrow[si];
            float tsum = 0.f;
            union { ushort u[8]; uint4 v; } pk;
            #pragma unroll
            for (int jj = 0; jj < 8; ++jj) {
                float p = __expf(sv[jj] - mi);
                tsum += p;
                pk.u[jj] = f2bf(p);
            }
            psum[jq][si] = tsum;
            *(uint4*)&Pp[si * 72 + jq * 8] = pk.v;
        }
        __syncthreads();                       // B4

        if (tid < 32) {
            float s = 0.f;
            #pragma unroll
            for (int t = 0; t < 8; ++t) s += psum[t][tid];
            lrow[tid] += s;
        }

        // ---- rescale accumulators, then O += P·V via MFMA ----
        {
            f32x4 al = *(const f32x4*)&arow[nloc];
            acc[0] *= al;
            acc[1] *= al;
            #pragma unroll
            for (int ks_ = 0; ks_ < 2; ++ks_) {
                int k0 = ks_ * 32;
                bf16x8 af = *(const bf16x8*)&Pp[(nsub * 16 + l15) * 72 + k0 + quad * 8];
                #pragma unroll
                for (int cs = 0; cs < 2; ++cs) {
                    int c = (cpair * 2 + cs) * 16 + l15;
                    bf16x8 bfr = *(const bf16x8*)&Vt[c * 72 + k0 + quad * 8];
                    acc[cs] = __builtin_amdgcn_mfma_f32_16x16x32_bf16(af, bfr, acc[cs], 0, 0, 0);
                }
            }
        }
        __syncthreads();                       // B5 (protect Vt/Pp/arow/psum for next tile)
    }

    // ---- epilogue: divide by l, transpose to Ot[c][n] in LDS ----
    {
        f32x4 l4 = *(const f32x4*)&lrow[nloc];
        f32x4 inv;
        inv[0] = 1.f / l4[0]; inv[1] = 1.f / l4[1];
        inv[2] = 1.f / l4[2]; inv[3] = 1.f / l4[3];
        #pragma unroll
        for (int cs = 0; cs < 2; ++cs) {
            int c = (cpair * 2 + cs) * 16 + l15;
            f32x4 o = acc[cs] * inv;
            *(f32x4*)&Ot[c * 36 + nloc] = o;
        }
    }
    __syncthreads();

    const float g2 = 2.f * gamma_p[0];
    const int nn = tid & 31, cg = tid >> 5;
    const size_t base = (size_t)b * 64 * NN + n0 + nn;
    #pragma unroll
    for (int u = 0; u < 8; ++u) {
        int c = cg * 8 + u;
        float oval = Ot[c * 36 + nn];
        size_t idx = base + (size_t)c * NN;
        out[idx] = x[idx] + 2.f * y[idx] + g2 * oval;
    }
}

extern "C" void kernel_launch(void* const* d_in, const int* in_sizes, int n_in,
                              void* d_out, int out_size, void* d_ws, size_t ws_size,
                              hipStream_t stream) {
    const float* x    = (const float*)d_in[0];
    const float* w1   = (const float*)d_in[1];
    const float* g1   = (const float*)d_in[2];
    const float* b1   = (const float*)d_in[3];
    const float* m1   = (const float*)d_in[4];
    const float* v1   = (const float*)d_in[5];
    const float* w2   = (const float*)d_in[6];
    const float* g2   = (const float*)d_in[7];
    const float* b2   = (const float*)d_in[8];
    const float* m2   = (const float*)d_in[9];
    const float* v2   = (const float*)d_in[10];
    const float* qw   = (const float*)d_in[11];
    const float* qb   = (const float*)d_in[12];
    const float* kw   = (const float*)d_in[13];
    const float* kb   = (const float*)d_in[14];
    const float* vw   = (const float*)d_in[15];
    const float* vb   = (const float*)d_in[16];
    const float* gam  = (const float*)d_in[17];
    float* outp = (float*)d_out;

    float* ws = (float*)d_ws;
    float*  y1 = ws;                          // 4*32*4096   = 524288 f
    float*  y  = ws + 524288;                 // 4*64*4096   = 1048576 f
    float*  qq = ws + 1572864;                // 4*4096*8    = 131072 f
    float*  kk = ws + 1703936;                // 4*4096*8    = 131072 f
    ushort* vv = (ushort*)(ws + 1835008);     // 4*64*4096 bf16 = 524288 f equiv

    conv3_bn_silu<64, 32, 4><<<dim3(16, 8, NB), 256, 0, stream>>>(
        x, w1, g1, b1, m1, v1, y1);
    conv3_bn_silu<32, 64, 8><<<dim3(16, 8, NB), 256, 0, stream>>>(
        y1, w2, g2, b2, m2, v2, y);
    qkv_proj<<<512, 256, 0, stream>>>(y, qw, qb, kw, kb, vw, vb, qq, kk, vv);
    flash_pam<<<512, 256, 0, stream>>>(qq, kk, vv, y, x, gam, outp);
}

// Round 4
// 262.587 us; speedup vs baseline: 1.7444x; 1.0032x over previous
//
#include <hip/hip_runtime.h>
#include <hip/hip_bf16.h>

#define NB 4
#define NN 4096
#define QT 32

typedef short  bf16x8 __attribute__((ext_vector_type(8)));
typedef float  f32x4  __attribute__((ext_vector_type(4)));

static __device__ __forceinline__ ushort f2bf(float f) {
    unsigned u = __float_as_uint(f);
    u += 0x7fffu + ((u >> 16) & 1u);          // RNE
    return (ushort)(u >> 16);
}
static __device__ __forceinline__ float bflo(unsigned w) { return __uint_as_float(w << 16); }
static __device__ __forceinline__ float bfhi(unsigned w) { return __uint_as_float(w & 0xffff0000u); }

// ---------------- conv 3x3 (pad 1) + BN + SiLU ----------------
// Weights staged in LDS once per block (kills per-ci s_load latency chains).
// in: [B][CIN][64][64] fp32, w: [COUT][CIN][3][3] fp32 -> out fp32
template <int CIN, int COUT, int CO_G>
__global__ __launch_bounds__(256) void conv3_bn_silu(
    const float* __restrict__ in,
    const float* __restrict__ w,
    const float* __restrict__ bng,
    const float* __restrict__ bnb,
    const float* __restrict__ bnm,
    const float* __restrict__ bnv,
    float* __restrict__ out)
{
    const int tid = threadIdx.x;
    const int r = tid >> 6, c = tid & 63;
    const int h   = blockIdx.x * 4 + r;
    const int co0 = blockIdx.y * CO_G;
    const int b   = blockIdx.z;

    __shared__ float wsm[CIN][CO_G * 9];
    for (int idx = tid; idx < CIN * CO_G * 9; idx += 256) {
        int ci = idx / (CO_G * 9), rest = idx % (CO_G * 9);
        int u = rest / 9, t = rest % 9;
        wsm[ci][rest] = w[((size_t)(co0 + u) * CIN + ci) * 9 + t];
    }

    int off[9]; float msk[9];
    #pragma unroll
    for (int dy = -1; dy <= 1; ++dy) {
        #pragma unroll
        for (int dx = -1; dx <= 1; ++dx) {
            int t = (dy + 1) * 3 + (dx + 1);
            int hh = h + dy, cx = c + dx;
            bool v = ((unsigned)hh < 64u) && ((unsigned)cx < 64u);
            int hc = min(max(hh, 0), 63), cc2 = min(max(cx, 0), 63);
            off[t] = hc * 64 + cc2;
            msk[t] = v ? 1.f : 0.f;
        }
    }
    __syncthreads();

    float acc[CO_G];
    #pragma unroll
    for (int u = 0; u < CO_G; ++u) acc[u] = 0.f;

    const float* inb = in + (size_t)b * CIN * 4096;

    #pragma unroll 4
    for (int ci = 0; ci < CIN; ++ci) {
        const float* ip = inb + (size_t)ci * 4096;
        float xv[9];
        #pragma unroll
        for (int t = 0; t < 9; ++t) xv[t] = ip[off[t]];
        float wr[CO_G * 9];
        #pragma unroll
        for (int j = 0; j < CO_G * 9 / 4; ++j)
            *(f32x4*)&wr[4 * j] = *(const f32x4*)&wsm[ci][4 * j];
        #pragma unroll
        for (int t = 0; t < 9; ++t) xv[t] *= msk[t];
        #pragma unroll
        for (int u = 0; u < CO_G; ++u)
            #pragma unroll
            for (int t = 0; t < 9; ++t)
                acc[u] = fmaf(wr[u * 9 + t], xv[t], acc[u]);
    }

    #pragma unroll
    for (int u = 0; u < CO_G; ++u) {
        int co = co0 + u;
        float scale = bng[co] / sqrtf(bnv[co] + 1e-5f);
        float bias  = bnb[co] - bnm[co] * scale;
        float pre = acc[u] * scale + bias;
        float res = pre / (1.f + __expf(-pre));
        out[(((size_t)b * COUT + co) * 64 + h) * 64 + c] = res;
    }
}

// ---------------- q/k/v 1x1 projections ----------------
// y: [B][64][4096] fp32 -> q: [B][4096][8] fp32, k: [B][4096][8] bf16,
//                          vt: [B][64][4096] bf16 (channel-major)
__global__ __launch_bounds__(256) void qkv_proj(
    const float* __restrict__ y,
    const float* __restrict__ qw, const float* __restrict__ qb,
    const float* __restrict__ kw, const float* __restrict__ kb,
    const float* __restrict__ vw, const float* __restrict__ vb,
    float* __restrict__ qo, ushort* __restrict__ ko, ushort* __restrict__ vt)
{
    __shared__ float W[80][64];
    __shared__ float Bv[80];
    const int tid = threadIdx.x;

    for (int idx = tid; idx < 512; idx += 256)  W[idx >> 6][idx & 63]        = qw[idx];
    for (int idx = tid; idx < 512; idx += 256)  W[8 + (idx >> 6)][idx & 63]  = kw[idx];
    for (int idx = tid; idx < 4096; idx += 256) W[16 + (idx >> 6)][idx & 63] = vw[idx];
    if (tid < 8)       Bv[tid] = qb[tid];
    else if (tid < 16) Bv[tid] = kb[tid - 8];
    else if (tid < 80) Bv[tid] = vb[tid - 16];
    __syncthreads();

    const int blk = blockIdx.x;           // 512 blocks: 4 b x 128 n-tiles of 32
    const int b  = blk >> 7;
    const int n0 = (blk & 127) * 32;
    const int nl = tid & 31;
    const int og = tid >> 5;              // 0..7, 10 output channels each
    const int n  = n0 + nl;

    float acc[10];
    #pragma unroll
    for (int u = 0; u < 10; ++u) acc[u] = Bv[og * 10 + u];

    const float* yb = y + (size_t)b * 64 * NN + n;
    for (int cc = 0; cc < 64; ++cc) {
        float yv = yb[(size_t)cc * NN];
        #pragma unroll
        for (int u = 0; u < 10; ++u) acc[u] = fmaf(W[og * 10 + u][cc], yv, acc[u]);
    }

    #pragma unroll
    for (int u = 0; u < 10; ++u) {
        int ch = og * 10 + u;
        if (ch < 8)       qo[((size_t)b * NN + n) * 8 + ch]         = acc[u];
        else if (ch < 16) ko[((size_t)b * NN + n) * 8 + (ch - 8)]   = f2bf(acc[u]);
        else              vt[((size_t)b * 64 + (ch - 16)) * NN + n] = f2bf(acc[u]);
    }
}

// ---------------- flash PAM v3: no-max softmax, staging-free K/V ----------------
// q: [B][4096][8] fp32, k8: [B][4096][8] bf16, vt: [B][64][4096] bf16
// y, x, out: [B][64][4096] fp32.  out = x + 2*y + 2*gamma*AttnOut
__global__ __launch_bounds__(256) void flash_pam(
    const float* __restrict__ q,
    const ushort* __restrict__ k8,
    const ushort* __restrict__ vt,
    const float* __restrict__ y,
    const float* __restrict__ x,
    const float* __restrict__ gamma_p,
    float* __restrict__ out)
{
    __shared__ __align__(16) ushort Pp[QT * 88];   // P[n][m] bf16, stride 88
    __shared__ float lrow[QT];
    __shared__ __align__(16) float Ot[64 * 36];    // epilogue transpose

    const int tid = threadIdx.x;
    const int b  = blockIdx.x >> 7;
    const int n0 = (blockIdx.x & 127) * QT;

    const int jg = tid & 15;      // j quad: j = jg*4+jj
    const int rg = tid >> 4;      // 0..15: rows rg*2, rg*2+1
    const int lane = tid & 63, w = tid >> 6;
    const int quad = lane >> 4, l15 = lane & 15;

    // two Q rows in registers (fp32)
    float Q0[8], Q1[8];
    {
        const float* qp = q + ((size_t)b * NN + n0 + rg * 2) * 8;
        #pragma unroll
        for (int d = 0; d < 8; ++d) { Q0[d] = qp[d]; Q1[d] = qp[8 + d]; }
    }

    f32x4 acc[2] = {{0.f,0.f,0.f,0.f},{0.f,0.f,0.f,0.f}};
    float lp0 = 0.f, lp1 = 0.f;

    const ushort* kg   = k8 + (size_t)b * NN * 8;
    const ushort* vrow = vt + (size_t)b * 64 * NN + (size_t)(w * 16 + l15) * NN;

    for (int kb = 0; kb < 64; ++kb) {
        const int m0 = kb * 64;

        // ---- S = q·k for 2 rows x 4 cols; K direct from global (bf16) ----
        float e0[4], e1[4];
        #pragma unroll
        for (int jj = 0; jj < 4; ++jj) {
            const uint4 kraw = *(const uint4*)(kg + (size_t)(m0 + jg * 4 + jj) * 8);
            float kf[8];
            kf[0] = bflo(kraw.x); kf[1] = bfhi(kraw.x);
            kf[2] = bflo(kraw.y); kf[3] = bfhi(kraw.y);
            kf[4] = bflo(kraw.z); kf[5] = bfhi(kraw.z);
            kf[6] = bflo(kraw.w); kf[7] = bfhi(kraw.w);
            float s0 = 0.f, s1 = 0.f;
            #pragma unroll
            for (int d = 0; d < 8; ++d) {
                s0 = fmaf(Q0[d], kf[d], s0);
                s1 = fmaf(Q1[d], kf[d], s1);
            }
            e0[jj] = __expf(s0);
            e1[jj] = __expf(s1);
        }
        lp0 += e0[0] + e0[1] + e0[2] + e0[3];
        lp1 += e1[0] + e1[1] + e1[2] + e1[3];
        {
            __hip_bfloat162 p00 = __float22bfloat162_rn(make_float2(e0[0], e0[1]));
            __hip_bfloat162 p01 = __float22bfloat162_rn(make_float2(e0[2], e0[3]));
            __hip_bfloat162 p10 = __float22bfloat162_rn(make_float2(e1[0], e1[1]));
            __hip_bfloat162 p11 = __float22bfloat162_rn(make_float2(e1[2], e1[3]));
            uint2 w0, w1;
            w0.x = *(unsigned*)&p00; w0.y = *(unsigned*)&p01;
            w1.x = *(unsigned*)&p10; w1.y = *(unsigned*)&p11;
            *(uint2*)&Pp[(rg * 2 + 0) * 88 + jg * 4] = w0;
            *(uint2*)&Pp[(rg * 2 + 1) * 88 + jg * 4] = w1;
        }
        __syncthreads();                  // B1: P visible

        // ---- O += P·V : A from LDS, B direct from global (L2) ----
        #pragma unroll
        for (int ks = 0; ks < 2; ++ks) {
            bf16x8 bfrag = *(const bf16x8*)(vrow + m0 + ks * 32 + quad * 8);
            bf16x8 a0 = *(const bf16x8*)&Pp[(0  + l15) * 88 + ks * 32 + quad * 8];
            bf16x8 a1 = *(const bf16x8*)&Pp[(16 + l15) * 88 + ks * 32 + quad * 8];
            acc[0] = __builtin_amdgcn_mfma_f32_16x16x32_bf16(a0, bfrag, acc[0], 0, 0, 0);
            acc[1] = __builtin_amdgcn_mfma_f32_16x16x32_bf16(a1, bfrag, acc[1], 0, 0, 0);
        }
        __syncthreads();                  // B2: MFMA reads done before next P write
    }

    // ---- l: reduce across the 16 j-threads (same quad within wave) ----
    #pragma unroll
    for (int off = 1; off < 16; off <<= 1) {
        lp0 += __shfl_xor(lp0, off, 64);
        lp1 += __shfl_xor(lp1, off, 64);
    }
    if (jg == 0) { lrow[rg * 2] = lp0; lrow[rg * 2 + 1] = lp1; }
    __syncthreads();

    // ---- epilogue: normalize + transpose via LDS ----
    #pragma unroll
    for (int h = 0; h < 2; ++h) {
        f32x4 o;
        #pragma unroll
        for (int u = 0; u < 4; ++u)
            o[u] = acc[h][u] / lrow[h * 16 + quad * 4 + u];
        *(f32x4*)&Ot[(w * 16 + l15) * 36 + h * 16 + quad * 4] = o;
    }
    __syncthreads();

    const float g2 = 2.f * gamma_p[0];
    const int nn = tid & 31, cq = tid >> 5;
    const size_t base = (size_t)b * 64 * NN + n0 + nn;
    #pragma unroll
    for (int u = 0; u < 8; ++u) {
        int c = cq * 8 + u;
        float ov = Ot[c * 36 + nn];
        size_t idx = base + (size_t)c * NN;
        out[idx] = x[idx] + 2.f * y[idx] + g2 * ov;
    }
}

extern "C" void kernel_launch(void* const* d_in, const int* in_sizes, int n_in,
                              void* d_out, int out_size, void* d_ws, size_t ws_size,
                              hipStream_t stream) {
    const float* x    = (const float*)d_in[0];
    const float* w1   = (const float*)d_in[1];
    const float* g1   = (const float*)d_in[2];
    const float* b1   = (const float*)d_in[3];
    const float* m1   = (const float*)d_in[4];
    const float* v1   = (const float*)d_in[5];
    const float* w2   = (const float*)d_in[6];
    const float* g2   = (const float*)d_in[7];
    const float* b2   = (const float*)d_in[8];
    const float* m2   = (const float*)d_in[9];
    const float* v2   = (const float*)d_in[10];
    const float* qw   = (const float*)d_in[11];
    const float* qb   = (const float*)d_in[12];
    const float* kw   = (const float*)d_in[13];
    const float* kb   = (const float*)d_in[14];
    const float* vw   = (const float*)d_in[15];
    const float* vb   = (const float*)d_in[16];
    const float* gam  = (const float*)d_in[17];
    float* outp = (float*)d_out;

    float* ws = (float*)d_ws;
    float*  y1 = ws;                          // 4*32*4096 f            = 524288
    float*  y  = ws + 524288;                 // 4*64*4096 f            = 1048576
    float*  qq = ws + 1572864;                // 4*4096*8 f             = 131072
    ushort* kk = (ushort*)(ws + 1703936);     // 4*4096*8 bf16          = 65536 f
    ushort* vv = (ushort*)(ws + 1769472);     // 4*64*4096 bf16         = 262144 f

    conv3_bn_silu<64, 32, 4><<<dim3(16, 8, NB), 256, 0, stream>>>(
        x, w1, g1, b1, m1, v1, y1);
    conv3_bn_silu<32, 64, 4><<<dim3(16, 16, NB), 256, 0, stream>>>(
        y1, w2, g2, b2, m2, v2, y);
    qkv_proj<<<512, 256, 0, stream>>>(y, qw, qb, kw, kb, vw, vb, qq, kk, vv);
    flash_pam<<<512, 256, 0, stream>>>(qq, kk, vv, y, x, gam, outp);
}

// Round 5
// 246.649 us; speedup vs baseline: 1.8572x; 1.0646x over previous
//
#include <hip/hip_runtime.h>
#include <hip/hip_bf16.h>

#define NB 4
#define NN 4096
#define QT 32
#define PST 144   // P row stride in ushorts (16B-aligned rows)

typedef short  bf16x8 __attribute__((ext_vector_type(8)));
typedef float  f32x4  __attribute__((ext_vector_type(4)));

static __device__ __forceinline__ ushort f2bf(float f) {
    unsigned u = __float_as_uint(f);
    u += 0x7fffu + ((u >> 16) & 1u);
    return (ushort)(u >> 16);
}
static __device__ __forceinline__ float bflo(unsigned w) { return __uint_as_float(w << 16); }
static __device__ __forceinline__ float bfhi(unsigned w) { return __uint_as_float(w & 0xffff0000u); }
static __device__ __forceinline__ unsigned bfbits(__hip_bfloat162 v) { return *(unsigned*)&v; }

// ---------------- conv 3x3 (pad 1) + BN + SiLU (round-3 form: s_load weights) ----------------
template <int CIN, int COUT, int CO_G>
__global__ __launch_bounds__(256) void conv3_bn_silu(
    const float* __restrict__ in,
    const float* __restrict__ w,
    const float* __restrict__ bng,
    const float* __restrict__ bnb,
    const float* __restrict__ bnm,
    const float* __restrict__ bnv,
    float* __restrict__ out)
{
    const int tid = threadIdx.x;
    const int r = tid >> 6, c = tid & 63;
    const int h  = blockIdx.x * 4 + r;
    const int co0 = blockIdx.y * CO_G;
    const int b  = blockIdx.z;

    int off[9]; float msk[9];
    #pragma unroll
    for (int dy = -1; dy <= 1; ++dy) {
        #pragma unroll
        for (int dx = -1; dx <= 1; ++dx) {
            int t = (dy + 1) * 3 + (dx + 1);
            int hh = h + dy, cx = c + dx;
            bool v = ((unsigned)hh < 64u) && ((unsigned)cx < 64u);
            int hc = min(max(hh, 0), 63), cc2 = min(max(cx, 0), 63);
            off[t] = hc * 64 + cc2;
            msk[t] = v ? 1.f : 0.f;
        }
    }

    float acc[CO_G];
    #pragma unroll
    for (int u = 0; u < CO_G; ++u) acc[u] = 0.f;

    const float* inb = in + (size_t)b * CIN * 4096;
    const float* wb  = w + (size_t)co0 * CIN * 9;

    for (int ci = 0; ci < CIN; ++ci) {
        float xv[9];
        const float* ip = inb + (size_t)ci * 4096;
        #pragma unroll
        for (int t = 0; t < 9; ++t) xv[t] = ip[off[t]] * msk[t];
        #pragma unroll
        for (int u = 0; u < CO_G; ++u) {
            const float* wp = wb + ((size_t)u * CIN + ci) * 9;   // block-uniform -> s_load
            #pragma unroll
            for (int t = 0; t < 9; ++t)
                acc[u] = fmaf(wp[t], xv[t], acc[u]);
        }
    }

    #pragma unroll
    for (int u = 0; u < CO_G; ++u) {
        int co = co0 + u;
        float scale = bng[co] / sqrtf(bnv[co] + 1e-5f);
        float bias  = bnb[co] - bnm[co] * scale;
        float pre = acc[u] * scale + bias;
        float res = pre / (1.f + __expf(-pre));
        out[(((size_t)b * COUT + co) * 64 + h) * 64 + c] = res;
    }
}

// ---------------- q/k/v 1x1 projections ----------------
// y: [B][64][4096] fp32 -> q: [B][4096][8] fp32, k: [B][4096][8] bf16,
//                          vt: [B][64][4096] bf16 (channel-major)
__global__ __launch_bounds__(256) void qkv_proj(
    const float* __restrict__ y,
    const float* __restrict__ qw, const float* __restrict__ qb,
    const float* __restrict__ kw, const float* __restrict__ kb,
    const float* __restrict__ vw, const float* __restrict__ vb,
    float* __restrict__ qo, ushort* __restrict__ ko, ushort* __restrict__ vt)
{
    __shared__ float W[80][64];
    __shared__ float Bv[80];
    const int tid = threadIdx.x;

    for (int idx = tid; idx < 512; idx += 256)  W[idx >> 6][idx & 63]        = qw[idx];
    for (int idx = tid; idx < 512; idx += 256)  W[8 + (idx >> 6)][idx & 63]  = kw[idx];
    for (int idx = tid; idx < 4096; idx += 256) W[16 + (idx >> 6)][idx & 63] = vw[idx];
    if (tid < 8)       Bv[tid] = qb[tid];
    else if (tid < 16) Bv[tid] = kb[tid - 8];
    else if (tid < 80) Bv[tid] = vb[tid - 16];
    __syncthreads();

    const int blk = blockIdx.x;           // 512 blocks: 4 b x 128 n-tiles of 32
    const int b  = blk >> 7;
    const int n0 = (blk & 127) * 32;
    const int nl = tid & 31;
    const int og = tid >> 5;              // 0..7, 10 output channels each
    const int n  = n0 + nl;

    float acc[10];
    #pragma unroll
    for (int u = 0; u < 10; ++u) acc[u] = Bv[og * 10 + u];

    const float* yb = y + (size_t)b * 64 * NN + n;
    for (int cc = 0; cc < 64; ++cc) {
        float yv = yb[(size_t)cc * NN];
        #pragma unroll
        for (int u = 0; u < 10; ++u) acc[u] = fmaf(W[og * 10 + u][cc], yv, acc[u]);
    }

    #pragma unroll
    for (int u = 0; u < 10; ++u) {
        int ch = og * 10 + u;
        if (ch < 8)       qo[((size_t)b * NN + n) * 8 + ch]         = acc[u];
        else if (ch < 16) ko[((size_t)b * NN + n) * 8 + (ch - 8)]   = f2bf(acc[u]);
        else              vt[((size_t)b * 64 + (ch - 16)) * NN + n] = f2bf(acc[u]);
    }
}

// ---------------- flash PAM, m-split, 1 barrier/iter, pipelined ----------------
// grid 1024: b(4) x ntile(128) x split(2). Each block: 32 q-rows, m in [sp*2048, +2048), 16 iters of 128.
// Writes UNNORMALIZED partial O (bf16, [b][c][n]) and partial l (fp32).
__global__ __launch_bounds__(256, 4) void flash_pam_split(
    const float* __restrict__ q,
    const ushort* __restrict__ k8,
    const ushort* __restrict__ vt,
    ushort* __restrict__ O0,
    ushort* __restrict__ O1,
    float* __restrict__ lpart)
{
    __shared__ __align__(16) ushort Pb[2][QT * PST];   // 2 x 9216 B ping-pong

    const int tid = threadIdx.x;
    const int bx = blockIdx.x;
    const int b  = bx >> 8;
    const int nt = (bx >> 1) & 127;
    const int sp = bx & 1;
    const int n0 = nt * QT;
    const int mb = sp * 2048;

    const int rg = tid >> 4;      // 0..15 -> rows 2rg, 2rg+1
    const int jg = tid & 15;      // m-cols jg*8 .. +7
    const int lane = tid & 63, w = tid >> 6;
    const int quad = lane >> 4, l15 = lane & 15;

    // Q rows (fp32) in registers
    float Q0[8], Q1[8];
    {
        const float* qp = q + ((size_t)b * NN + n0 + 2 * rg) * 8;
        #pragma unroll
        for (int d = 0; d < 8; ++d) { Q0[d] = qp[d]; Q1[d] = qp[8 + d]; }
    }

    const ushort* kg = k8 + ((size_t)b * NN + mb) * 8;
    const ushort* vg = vt + ((size_t)b * 64 + w * 16 + l15) * NN + mb;

    f32x4 acc0 = {0.f,0.f,0.f,0.f}, acc1 = {0.f,0.f,0.f,0.f};
    float lp0 = 0.f, lp1 = 0.f;

    // preload K(0): 8 rows x 8 bf16 = 8 x uint4
    uint4 kq[8];
    {
        const ushort* kn = kg + jg * 64;
        #pragma unroll
        for (int jj = 0; jj < 8; ++jj) kq[jj] = *(const uint4*)(kn + jj * 8);
    }

    #pragma unroll 2
    for (int t = 0; t < 16; ++t) {
        // V B-fragments for this iter (consumed after the barrier)
        bf16x8 vf[4];
        {
            const ushort* vp = vg + (size_t)t * 128;
            #pragma unroll
            for (int ks = 0; ks < 4; ++ks)
                vf[ks] = *(const bf16x8*)(vp + ks * 32 + quad * 8);
        }

        // S = q.k (VALU) + exp
        float e0[8], e1[8];
        #pragma unroll
        for (int jj = 0; jj < 8; ++jj) {
            uint4 kr = kq[jj];
            float kf[8];
            kf[0] = bflo(kr.x); kf[1] = bfhi(kr.x);
            kf[2] = bflo(kr.y); kf[3] = bfhi(kr.y);
            kf[4] = bflo(kr.z); kf[5] = bfhi(kr.z);
            kf[6] = bflo(kr.w); kf[7] = bfhi(kr.w);
            float s0 = 0.f, s1 = 0.f;
            #pragma unroll
            for (int d = 0; d < 8; ++d) {
                s0 = fmaf(Q0[d], kf[d], s0);
                s1 = fmaf(Q1[d], kf[d], s1);
            }
            e0[jj] = __expf(s0);
            e1[jj] = __expf(s1);
        }
        // prefetch K(t+1) now that kq is dead
        if (t < 15) {
            const ushort* kn = kg + (size_t)(t + 1) * 1024 + jg * 64;
            #pragma unroll
            for (int jj = 0; jj < 8; ++jj) kq[jj] = *(const uint4*)(kn + jj * 8);
        }

        #pragma unroll
        for (int jj = 0; jj < 8; ++jj) { lp0 += e0[jj]; lp1 += e1[jj]; }

        // pack + write P rows (bf16)
        {
            uint4 pv0, pv1;
            pv0.x = bfbits(__float22bfloat162_rn(make_float2(e0[0], e0[1])));
            pv0.y = bfbits(__float22bfloat162_rn(make_float2(e0[2], e0[3])));
            pv0.z = bfbits(__float22bfloat162_rn(make_float2(e0[4], e0[5])));
            pv0.w = bfbits(__float22bfloat162_rn(make_float2(e0[6], e0[7])));
            pv1.x = bfbits(__float22bfloat162_rn(make_float2(e1[0], e1[1])));
            pv1.y = bfbits(__float22bfloat162_rn(make_float2(e1[2], e1[3])));
            pv1.z = bfbits(__float22bfloat162_rn(make_float2(e1[4], e1[5])));
            pv1.w = bfbits(__float22bfloat162_rn(make_float2(e1[6], e1[7])));
            ushort* pw = &Pb[t & 1][2 * rg * PST + jg * 8];
            *(uint4*)pw = pv0;
            *(uint4*)(pw + PST) = pv1;
        }
        __syncthreads();

        // O += P.V via MFMA
        {
            const ushort* pb = Pb[t & 1];
            #pragma unroll
            for (int ks = 0; ks < 4; ++ks) {
                bf16x8 a0 = *(const bf16x8*)&pb[l15 * PST + ks * 32 + quad * 8];
                bf16x8 a1 = *(const bf16x8*)&pb[(16 + l15) * PST + ks * 32 + quad * 8];
                acc0 = __builtin_amdgcn_mfma_f32_16x16x32_bf16(a0, vf[ks], acc0, 0, 0, 0);
                acc1 = __builtin_amdgcn_mfma_f32_16x16x32_bf16(a1, vf[ks], acc1, 0, 0, 0);
            }
        }
    }

    // partial l: reduce over the 16 jg-threads (contiguous 16 lanes)
    #pragma unroll
    for (int off = 1; off < 16; off <<= 1) {
        lp0 += __shfl_xor(lp0, off, 16);
        lp1 += __shfl_xor(lp1, off, 16);
    }
    if (jg == 0) {
        float* lp = lpart + ((size_t)(sp * 4 + b)) * NN + n0 + 2 * rg;
        lp[0] = lp0; lp[1] = lp1;
    }

    // partial O: transpose via LDS (Pb[0] region; final MFMA read Pb[1] - disjoint)
    float* Ot = (float*)&Pb[0][0];   // [c][n], stride 36
    *(f32x4*)&Ot[(w * 16 + l15) * 36 + 0 * 16 + quad * 4] = acc0;
    *(f32x4*)&Ot[(w * 16 + l15) * 36 + 1 * 16 + quad * 4] = acc1;
    __syncthreads();

    ushort* Od = (sp ? O1 : O0);
    const int nn = tid & 31, cq = tid >> 5;
    #pragma unroll
    for (int u = 0; u < 8; ++u) {
        int c = cq * 8 + u;
        Od[((size_t)b * 64 + c) * NN + n0 + nn] = f2bf(Ot[c * 36 + nn]);
    }
}

// ---------------- merge partials + residual epilogue ----------------
__global__ __launch_bounds__(256) void merge_out(
    const ushort* __restrict__ O0, const ushort* __restrict__ O1,
    const float* __restrict__ lpart,
    const float* __restrict__ x, const float* __restrict__ y,
    const float* __restrict__ gamma_p, float* __restrict__ out)
{
    const size_t base4 = ((size_t)blockIdx.x * 256 + threadIdx.x) * 4;
    const int n = (int)(base4 & 4095);
    const int b = (int)(base4 >> 18);
    const float g2 = 2.f * gamma_p[0];

    uint2 r0 = *(const uint2*)(O0 + base4);
    uint2 r1 = *(const uint2*)(O1 + base4);
    const float* l0 = lpart + (size_t)b * NN + n;
    const float* l1 = lpart + (size_t)(4 + b) * NN + n;

    f32x4 o;
    o[0] = bflo(r0.x) + bflo(r1.x);
    o[1] = bfhi(r0.x) + bfhi(r1.x);
    o[2] = bflo(r0.y) + bflo(r1.y);
    o[3] = bfhi(r0.y) + bfhi(r1.y);

    f32x4 xv = *(const f32x4*)(x + base4);
    f32x4 yv = *(const f32x4*)(y + base4);
    f32x4 res;
    #pragma unroll
    for (int u = 0; u < 4; ++u)
        res[u] = xv[u] + 2.f * yv[u] + g2 * o[u] / (l0[u] + l1[u]);
    *(f32x4*)(out + base4) = res;
}

extern "C" void kernel_launch(void* const* d_in, const int* in_sizes, int n_in,
                              void* d_out, int out_size, void* d_ws, size_t ws_size,
                              hipStream_t stream) {
    const float* x    = (const float*)d_in[0];
    const float* w1   = (const float*)d_in[1];
    const float* g1   = (const float*)d_in[2];
    const float* b1   = (const float*)d_in[3];
    const float* m1   = (const float*)d_in[4];
    const float* v1   = (const float*)d_in[5];
    const float* w2   = (const float*)d_in[6];
    const float* g2   = (const float*)d_in[7];
    const float* b2   = (const float*)d_in[8];
    const float* m2   = (const float*)d_in[9];
    const float* v2   = (const float*)d_in[10];
    const float* qw   = (const float*)d_in[11];
    const float* qb   = (const float*)d_in[12];
    const float* kw   = (const float*)d_in[13];
    const float* kb   = (const float*)d_in[14];
    const float* vw   = (const float*)d_in[15];
    const float* vb   = (const float*)d_in[16];
    const float* gam  = (const float*)d_in[17];
    float* outp = (float*)d_out;

    float* ws = (float*)d_ws;
    float*  y1 = ws;                          // 524288 f  (dead after conv2 -> reused as O0)
    float*  y  = ws + 524288;                 // 1048576 f
    float*  qq = ws + 1572864;                // 131072 f
    ushort* kk = (ushort*)(ws + 1703936);     // 131072 ush
    ushort* vv = (ushort*)(ws + 1769472);     // 1048576 ush
    ushort* O0 = (ushort*)y1;                 // 1048576 ush bf16 (== y1 footprint exactly)
    ushort* O1 = (ushort*)(ws + 2293760);     // 1048576 ush = 524288 f
    float*  lp = ws + 2818048;                // 32768 f      (end: 2850816 f = 11.40 MB)

    conv3_bn_silu<64, 32, 4><<<dim3(16, 8, NB), 256, 0, stream>>>(
        x, w1, g1, b1, m1, v1, y1);
    conv3_bn_silu<32, 64, 8><<<dim3(16, 8, NB), 256, 0, stream>>>(
        y1, w2, g2, b2, m2, v2, y);
    qkv_proj<<<512, 256, 0, stream>>>(y, qw, qb, kw, kb, vw, vb, qq, kk, vv);
    flash_pam_split<<<1024, 256, 0, stream>>>(qq, kk, vv, O0, O1, lp);
    merge_out<<<1024, 256, 0, stream>>>(O0, O1, lp, x, y, gam, outp);
}

// Round 6
// 163.054 us; speedup vs baseline: 2.8093x; 1.5127x over previous
//
#include <hip/hip_runtime.h>
#include <hip/hip_bf16.h>

#define NB 4
#define NN 4096
#define QT 32
#define PST 144   // P row stride in ushorts

typedef short  bf16x8 __attribute__((ext_vector_type(8)));
typedef float  f32x4  __attribute__((ext_vector_type(4)));

static __device__ __forceinline__ ushort f2bf(float f) {
    unsigned u = __float_as_uint(f);
    u += 0x7fffu + ((u >> 16) & 1u);
    return (ushort)(u >> 16);
}
static __device__ __forceinline__ float bflo(unsigned w) { return __uint_as_float(w << 16); }
static __device__ __forceinline__ float bfhi(unsigned w) { return __uint_as_float(w & 0xffff0000u); }
static __device__ __forceinline__ unsigned bfbits(__hip_bfloat162 v) { return *(unsigned*)&v; }

// ---------------- prep: x -> xt (channel-last bf16), weights -> reordered bf16 ----------------
// xt[b][n][ci] ; W1r[co][tap*64+ci] (32x576) ; W2r[co][tap*32+ci] (64x288)
__global__ __launch_bounds__(256) void prep(
    const float* __restrict__ x, const float* __restrict__ w1, const float* __restrict__ w2,
    ushort* __restrict__ xt, ushort* __restrict__ W1r, ushort* __restrict__ W2r)
{
    const int tid = threadIdx.x;
    const int blk = blockIdx.x;
    if (blk < 256) {
        __shared__ float Ts[64][66];
        const int b = blk >> 6, n0 = (blk & 63) * 64;
        const int wv = tid >> 6, lane = tid & 63;
        #pragma unroll
        for (int i = 0; i < 16; ++i) {
            int ci = i * 4 + wv, nn = lane;
            Ts[ci][nn] = x[((size_t)b * 64 + ci) * NN + n0 + nn];
        }
        __syncthreads();
        #pragma unroll
        for (int i = 0; i < 16; ++i) {
            int nn = i * 4 + wv, ci = lane;
            xt[((size_t)b * NN + n0 + nn) * 64 + ci] = f2bf(Ts[ci][nn]);
        }
    } else if (blk < 258) {
        const int base = (blk - 256) * 9216;
        #pragma unroll
        for (int i = 0; i < 36; ++i) {
            int e = base + i * 256 + tid;
            int co = e / 576, k = e % 576, tap = k >> 6, ci = k & 63;
            W1r[e] = f2bf(w1[((size_t)co * 64 + ci) * 9 + tap]);
        }
    } else {
        const int base = (blk - 258) * 9216;
        #pragma unroll
        for (int i = 0; i < 36; ++i) {
            int e = base + i * 256 + tid;
            int co = e / 288, k = e % 288, tap = k >> 5, ci = k & 31;
            W2r[e] = f2bf(w2[((size_t)co * 32 + ci) * 9 + tap]);
        }
    }
}

// ---------------- conv1: 64ci -> 32co, MFMA implicit GEMM, one h-row per block ----------------
// xt: [B][4096][64] bf16 -> y1t: [B][4096][32] bf16
__global__ __launch_bounds__(256) void conv1_mfma(
    const ushort* __restrict__ xt, const ushort* __restrict__ W1r,
    const float* __restrict__ bng, const float* __restrict__ bnb,
    const float* __restrict__ bnm, const float* __restrict__ bnv,
    ushort* __restrict__ y1t)
{
    __shared__ __align__(16) ushort As[32 * 600];        // 38,400 B
    __shared__ __align__(16) ushort Xs[24 * 66 * 8];     // 25,344 B  [(r*8+cc)][wpos][8]

    const int tid = threadIdx.x;
    const int h = blockIdx.x, b = blockIdx.y;

    #pragma unroll
    for (int i = 0; i < 9; ++i) {
        int cid = i * 256 + tid;                  // < 2304
        int row = cid / 72, off = cid % 72;
        *(uint4*)&As[row * 600 + off * 8] = *(const uint4*)(W1r + (size_t)cid * 8);
    }
    #pragma unroll
    for (int r = 0; r < 3; ++r) {
        int gh = h - 1 + r;
        #pragma unroll
        for (int i = 0; i < 2; ++i) {
            int cid = i * 256 + tid;              // < 512
            int w_ = cid >> 3, cc = cid & 7;
            uint4 v = {0, 0, 0, 0};
            if ((unsigned)gh < 64u)
                v = *(const uint4*)(xt + ((size_t)(b * NN + gh * 64) * 64) + (size_t)cid * 8);
            *(uint4*)&Xs[((r * 8 + cc) * 66 + (w_ + 1)) * 8] = v;
        }
    }
    if (tid < 48) {
        int r = tid >> 4, q = tid & 15, cc = q >> 1, side = (q & 1) * 65;
        uint4 z = {0, 0, 0, 0};
        *(uint4*)&Xs[((r * 8 + cc) * 66 + side) * 8] = z;
    }
    __syncthreads();

    const int lane = tid & 63, wv = tid >> 6;
    const int quad = lane >> 4, l15 = lane & 15;
    const int ch = wv & 1, ph = wv >> 1;

    f32x4 acc[2] = {{0.f,0.f,0.f,0.f},{0.f,0.f,0.f,0.f}};
    #pragma unroll
    for (int kk = 0; kk < 18; ++kk) {
        const int tap = kk >> 1;
        const int dyr = tap / 3, dx = tap % 3;
        bf16x8 af = *(const bf16x8*)&As[(ch * 16 + l15) * 600 + kk * 32 + quad * 8];
        #pragma unroll
        for (int s = 0; s < 2; ++s) {
            int p = ph * 32 + s * 16 + l15;
            bf16x8 bf = *(const bf16x8*)&Xs[((dyr * 8 + (kk & 1) * 4 + quad) * 66 + p + dx) * 8];
            acc[s] = __builtin_amdgcn_mfma_f32_16x16x32_bf16(af, bf, acc[s], 0, 0, 0);
        }
    }

    const int cb = ch * 16 + quad * 4;
    float sc[4], bs[4];
    #pragma unroll
    for (int r = 0; r < 4; ++r) {
        int co = cb + r;
        sc[r] = bng[co] / sqrtf(bnv[co] + 1e-5f);
        bs[r] = bnb[co] - bnm[co] * sc[r];
    }
    #pragma unroll
    for (int s = 0; s < 2; ++s) {
        int p = ph * 32 + s * 16 + l15;
        ushort u4[4];
        #pragma unroll
        for (int r = 0; r < 4; ++r) {
            float pre = acc[s][r] * sc[r] + bs[r];
            u4[r] = f2bf(pre / (1.f + __expf(-pre)));
        }
        *(uint2*)&y1t[((size_t)(b * NN + h * 64 + p)) * 32 + cb] = *(uint2*)u4;
    }
}

// ---------------- conv2: 32ci -> 64co, MFMA implicit GEMM ----------------
// y1t: [B][4096][32] bf16 -> y: [B][64][4096] fp32
__global__ __launch_bounds__(256) void conv2_mfma(
    const ushort* __restrict__ y1t, const ushort* __restrict__ W2r,
    const float* __restrict__ bng, const float* __restrict__ bnb,
    const float* __restrict__ bnm, const float* __restrict__ bnv,
    float* __restrict__ y)
{
    __shared__ __align__(16) ushort As[64 * 312];        // 39,936 B
    __shared__ __align__(16) ushort Xs[12 * 66 * 8];     // 12,672 B

    const int tid = threadIdx.x;
    const int h = blockIdx.x, b = blockIdx.y;

    #pragma unroll
    for (int i = 0; i < 9; ++i) {
        int cid = i * 256 + tid;                  // < 2304
        int row = cid / 36, off = cid % 36;
        *(uint4*)&As[row * 312 + off * 8] = *(const uint4*)(W2r + (size_t)cid * 8);
    }
    #pragma unroll
    for (int r = 0; r < 3; ++r) {
        int gh = h - 1 + r;
        int cid = tid;                            // < 256
        int w_ = cid >> 2, cc = cid & 3;
        uint4 v = {0, 0, 0, 0};
        if ((unsigned)gh < 64u)
            v = *(const uint4*)(y1t + ((size_t)(b * NN + gh * 64) * 32) + (size_t)cid * 8);
        *(uint4*)&Xs[((r * 4 + cc) * 66 + (w_ + 1)) * 8] = v;
    }
    if (tid < 24) {
        int r = tid >> 3, q = tid & 7, cc = q >> 1, side = (q & 1) * 65;
        uint4 z = {0, 0, 0, 0};
        *(uint4*)&Xs[((r * 4 + cc) * 66 + side) * 8] = z;
    }
    __syncthreads();

    const int lane = tid & 63, wv = tid >> 6;
    const int quad = lane >> 4, l15 = lane & 15;

    f32x4 acc[4] = {{0.f,0.f,0.f,0.f},{0.f,0.f,0.f,0.f},{0.f,0.f,0.f,0.f},{0.f,0.f,0.f,0.f}};
    #pragma unroll
    for (int kk = 0; kk < 9; ++kk) {
        const int dyr = kk / 3, dx = kk % 3;
        bf16x8 af = *(const bf16x8*)&As[(wv * 16 + l15) * 312 + kk * 32 + quad * 8];
        #pragma unroll
        for (int s = 0; s < 4; ++s) {
            int p = s * 16 + l15;
            bf16x8 bf = *(const bf16x8*)&Xs[((dyr * 4 + quad) * 66 + p + dx) * 8];
            acc[s] = __builtin_amdgcn_mfma_f32_16x16x32_bf16(af, bf, acc[s], 0, 0, 0);
        }
    }

    const int cb = wv * 16 + quad * 4;
    float sc[4], bs[4];
    #pragma unroll
    for (int r = 0; r < 4; ++r) {
        int co = cb + r;
        sc[r] = bng[co] / sqrtf(bnv[co] + 1e-5f);
        bs[r] = bnb[co] - bnm[co] * sc[r];
    }
    #pragma unroll
    for (int s = 0; s < 4; ++s) {
        int p = s * 16 + l15;
        #pragma unroll
        for (int r = 0; r < 4; ++r) {
            float pre = acc[s][r] * sc[r] + bs[r];
            y[((size_t)(b * 64 + cb + r)) * NN + h * 64 + p] = pre / (1.f + __expf(-pre));
        }
    }
}

// ---------------- q/k/v 1x1 projections ----------------
// vt written with within-128 k-permutation s = (m%16)*8 + m/16 to match flash fragment order
__global__ __launch_bounds__(256) void qkv_proj(
    const float* __restrict__ y,
    const float* __restrict__ qw, const float* __restrict__ qb,
    const float* __restrict__ kw, const float* __restrict__ kb,
    const float* __restrict__ vw, const float* __restrict__ vb,
    float* __restrict__ qo, ushort* __restrict__ ko, ushort* __restrict__ vt)
{
    __shared__ float W[80][64];
    __shared__ float Bv[80];
    const int tid = threadIdx.x;

    for (int idx = tid; idx < 512; idx += 256)  W[idx >> 6][idx & 63]        = qw[idx];
    for (int idx = tid; idx < 512; idx += 256)  W[8 + (idx >> 6)][idx & 63]  = kw[idx];
    for (int idx = tid; idx < 4096; idx += 256) W[16 + (idx >> 6)][idx & 63] = vw[idx];
    if (tid < 8)       Bv[tid] = qb[tid];
    else if (tid < 16) Bv[tid] = kb[tid - 8];
    else if (tid < 80) Bv[tid] = vb[tid - 16];
    __syncthreads();

    const int blk = blockIdx.x;
    const int b  = blk >> 7;
    const int n0 = (blk & 127) * 32;
    const int nl = tid & 31;
    const int og = tid >> 5;
    const int n  = n0 + nl;

    float acc[10];
    #pragma unroll
    for (int u = 0; u < 10; ++u) acc[u] = Bv[og * 10 + u];

    const float* yb = y + (size_t)b * 64 * NN + n;
    for (int cc = 0; cc < 64; ++cc) {
        float yv = yb[(size_t)cc * NN];
        #pragma unroll
        for (int u = 0; u < 10; ++u) acc[u] = fmaf(W[og * 10 + u][cc], yv, acc[u]);
    }

    const int nperm = (n & ~127) + (n & 15) * 8 + ((n >> 4) & 7);
    #pragma unroll
    for (int u = 0; u < 10; ++u) {
        int ch = og * 10 + u;
        if (ch < 8)       qo[((size_t)b * NN + n) * 8 + ch]       = acc[u];
        else if (ch < 16) ko[((size_t)b * NN + n) * 8 + (ch - 8)] = f2bf(acc[u]);
        else              vt[((size_t)b * 64 + (ch - 16)) * NN + nperm] = f2bf(acc[u]);
    }
}

// ---------------- flash PAM, m-split, LDS-staged K ping-pong ----------------
__global__ __launch_bounds__(256, 4) void flash_pam_split(
    const float* __restrict__ q,
    const ushort* __restrict__ k8,
    const ushort* __restrict__ vt,
    ushort* __restrict__ O0,
    ushort* __restrict__ O1,
    float* __restrict__ lpart)
{
    __shared__ __align__(16) ushort Pb[2][QT * PST];   // 2 x 9216 B
    __shared__ __align__(16) ushort Ks[2][128 * 8];    // 2 x 2048 B
    __shared__ float lrow[QT];

    const int tid = threadIdx.x;
    const int bx = blockIdx.x;
    const int b  = bx >> 8;
    const int nt = (bx >> 1) & 127;
    const int sp = bx & 1;
    const int n0 = nt * QT;
    const int mb = sp * 2048;

    const int rg = tid >> 4;      // rows 2rg, 2rg+1
    const int jg = tid & 15;      // cols jg + 16*jj (k-permuted)
    const int lane = tid & 63, w = tid >> 6;
    const int quad = lane >> 4, l15 = lane & 15;

    float Q0[8], Q1[8];
    {
        const float* qp = q + ((size_t)b * NN + n0 + 2 * rg) * 8;
        #pragma unroll
        for (int d = 0; d < 8; ++d) { Q0[d] = qp[d]; Q1[d] = qp[8 + d]; }
    }

    const ushort* kg = k8 + ((size_t)b * NN + mb) * 8;
    const ushort* vg = vt + ((size_t)b * 64 + w * 16 + l15) * NN + mb;

    f32x4 acc0 = {0.f,0.f,0.f,0.f}, acc1 = {0.f,0.f,0.f,0.f};
    float lp0 = 0.f, lp1 = 0.f;

    if (tid < 128) *(uint4*)&Ks[0][tid * 8] = *(const uint4*)(kg + (size_t)tid * 8);
    __syncthreads();

    #pragma unroll 2
    for (int t = 0; t < 16; ++t) {
        // V B-fragments (global, consumed post-barrier)
        bf16x8 vf[4];
        {
            const ushort* vp = vg + (size_t)t * 128;
            #pragma unroll
            for (int ks = 0; ks < 4; ++ks)
                vf[ks] = *(const bf16x8*)(vp + ks * 32 + quad * 8);
        }
        // K(t+1) global prefetch into regs
        uint4 kpre = {0, 0, 0, 0};
        if (tid < 128 && t < 15)
            kpre = *(const uint4*)(kg + ((size_t)(t + 1) * 128 + tid) * 8);

        // S = q.k from LDS K (cols jg+16jj), exp
        float e0[8], e1[8];
        #pragma unroll
        for (int jj = 0; jj < 8; ++jj) {
            uint4 kr = *(const uint4*)&Ks[t & 1][(jg + 16 * jj) * 8];
            float kf[8];
            kf[0] = bflo(kr.x); kf[1] = bfhi(kr.x);
            kf[2] = bflo(kr.y); kf[3] = bfhi(kr.y);
            kf[4] = bflo(kr.z); kf[5] = bfhi(kr.z);
            kf[6] = bflo(kr.w); kf[7] = bfhi(kr.w);
            float s0 = 0.f, s1 = 0.f;
            #pragma unroll
            for (int d = 0; d < 8; ++d) {
                s0 = fmaf(Q0[d], kf[d], s0);
                s1 = fmaf(Q1[d], kf[d], s1);
            }
            e0[jj] = __expf(s0);
            e1[jj] = __expf(s1);
        }
        #pragma unroll
        for (int jj = 0; jj < 8; ++jj) { lp0 += e0[jj]; lp1 += e1[jj]; }

        // write K(t+1) to LDS ping-pong
        if (tid < 128 && t < 15) *(uint4*)&Ks[(t + 1) & 1][tid * 8] = kpre;

        // pack P (storage index s = jg*8+jj matches vt permutation)
        {
            uint4 pv0, pv1;
            pv0.x = bfbits(__float22bfloat162_rn(make_float2(e0[0], e0[1])));
            pv0.y = bfbits(__float22bfloat162_rn(make_float2(e0[2], e0[3])));
            pv0.z = bfbits(__float22bfloat162_rn(make_float2(e0[4], e0[5])));
            pv0.w = bfbits(__float22bfloat162_rn(make_float2(e0[6], e0[7])));
            pv1.x = bfbits(__float22bfloat162_rn(make_float2(e1[0], e1[1])));
            pv1.y = bfbits(__float22bfloat162_rn(make_float2(e1[2], e1[3])));
            pv1.z = bfbits(__float22bfloat162_rn(make_float2(e1[4], e1[5])));
            pv1.w = bfbits(__float22bfloat162_rn(make_float2(e1[6], e1[7])));
            ushort* pw = &Pb[t & 1][2 * rg * PST + jg * 8];
            *(uint4*)pw = pv0;
            *(uint4*)(pw + PST) = pv1;
        }
        __syncthreads();

        // O += P.V
        {
            const ushort* pb = Pb[t & 1];
            #pragma unroll
            for (int ks = 0; ks < 4; ++ks) {
                bf16x8 a0 = *(const bf16x8*)&pb[l15 * PST + ks * 32 + quad * 8];
                bf16x8 a1 = *(const bf16x8*)&pb[(16 + l15) * PST + ks * 32 + quad * 8];
                acc0 = __builtin_amdgcn_mfma_f32_16x16x32_bf16(a0, vf[ks], acc0, 0, 0, 0);
                acc1 = __builtin_amdgcn_mfma_f32_16x16x32_bf16(a1, vf[ks], acc1, 0, 0, 0);
            }
        }
    }

    #pragma unroll
    for (int off = 1; off < 16; off <<= 1) {
        lp0 += __shfl_xor(lp0, off, 16);
        lp1 += __shfl_xor(lp1, off, 16);
    }
    if (jg == 0) {
        float* lpw = lpart + ((size_t)(sp * 4 + b)) * NN + n0 + 2 * rg;
        lpw[0] = lp0; lpw[1] = lp1;
    }

    float* Ot = (float*)&Pb[0][0];   // [c][n], stride 36 (last MFMA read Pb[1])
    *(f32x4*)&Ot[(w * 16 + l15) * 36 + 0 * 16 + quad * 4] = acc0;
    *(f32x4*)&Ot[(w * 16 + l15) * 36 + 1 * 16 + quad * 4] = acc1;
    __syncthreads();

    ushort* Od = (sp ? O1 : O0);
    const int nn = tid & 31, cq = tid >> 5;
    #pragma unroll
    for (int u = 0; u < 8; ++u) {
        int c = cq * 8 + u;
        Od[((size_t)b * 64 + c) * NN + n0 + nn] = f2bf(Ot[c * 36 + nn]);
    }
}

// ---------------- merge partials + residual epilogue ----------------
__global__ __launch_bounds__(256) void merge_out(
    const ushort* __restrict__ O0, const ushort* __restrict__ O1,
    const float* __restrict__ lpart,
    const float* __restrict__ x, const float* __restrict__ y,
    const float* __restrict__ gamma_p, float* __restrict__ out)
{
    const size_t base4 = ((size_t)blockIdx.x * 256 + threadIdx.x) * 4;
    const int n = (int)(base4 & 4095);
    const int b = (int)(base4 >> 18);
    const float g2 = 2.f * gamma_p[0];

    uint2 r0 = *(const uint2*)(O0 + base4);
    uint2 r1 = *(const uint2*)(O1 + base4);
    const float* l0 = lpart + (size_t)b * NN + n;
    const float* l1 = lpart + (size_t)(4 + b) * NN + n;

    f32x4 o;
    o[0] = bflo(r0.x) + bflo(r1.x);
    o[1] = bfhi(r0.x) + bfhi(r1.x);
    o[2] = bflo(r0.y) + bflo(r1.y);
    o[3] = bfhi(r0.y) + bfhi(r1.y);

    f32x4 xv = *(const f32x4*)(x + base4);
    f32x4 yv = *(const f32x4*)(y + base4);
    f32x4 res;
    #pragma unroll
    for (int u = 0; u < 4; ++u)
        res[u] = xv[u] + 2.f * yv[u] + g2 * o[u] / (l0[u] + l1[u]);
    *(f32x4*)(out + base4) = res;
}

extern "C" void kernel_launch(void* const* d_in, const int* in_sizes, int n_in,
                              void* d_out, int out_size, void* d_ws, size_t ws_size,
                              hipStream_t stream) {
    const float* x    = (const float*)d_in[0];
    const float* w1   = (const float*)d_in[1];
    const float* g1   = (const float*)d_in[2];
    const float* b1   = (const float*)d_in[3];
    const float* m1   = (const float*)d_in[4];
    const float* v1   = (const float*)d_in[5];
    const float* w2   = (const float*)d_in[6];
    const float* g2   = (const float*)d_in[7];
    const float* b2   = (const float*)d_in[8];
    const float* m2   = (const float*)d_in[9];
    const float* v2   = (const float*)d_in[10];
    const float* qw   = (const float*)d_in[11];
    const float* qb   = (const float*)d_in[12];
    const float* kw   = (const float*)d_in[13];
    const float* kb   = (const float*)d_in[14];
    const float* vw   = (const float*)d_in[15];
    const float* vb   = (const float*)d_in[16];
    const float* gam  = (const float*)d_in[17];
    float* outp = (float*)d_out;

    float* ws = (float*)d_ws;
    ushort* xt  = (ushort*)ws;                 // 1,048,576 ush (524,288 f); O1 overlays after conv1
    float*  y   = ws + 524288;                 // 1,048,576 f
    float*  qq  = ws + 1572864;                // 131,072 f
    ushort* kk  = (ushort*)(ws + 1703936);     // 131,072 ush
    ushort* vv  = (ushort*)(ws + 1769472);     // 1,048,576 ush
    float*  lp  = ws + 2293760;                // 32,768 f
    float*  S   = ws + 2326528;                // 524,288 f scratch
    ushort* y1t = (ushort*)S;                  // 524,288 ush
    ushort* W1r = (ushort*)(S + 262144);       // 18,432 ush
    ushort* W2r = (ushort*)(S + 271360);       // 18,432 ush
    ushort* O0  = (ushort*)S;                  // flash overwrites S (y1t/W1r/W2r dead)
    ushort* O1  = xt;                          // xt dead after conv1
    // total: 2,850,816 f = 11.40 MB (same as round-5 proven footprint)

    prep<<<260, 256, 0, stream>>>(x, w1, w2, xt, W1r, W2r);
    conv1_mfma<<<dim3(64, NB), 256, 0, stream>>>(xt, W1r, g1, b1, m1, v1, y1t);
    conv2_mfma<<<dim3(64, NB), 256, 0, stream>>>(y1t, W2r, g2, b2, m2, v2, y);
    qkv_proj<<<512, 256, 0, stream>>>(y, qw, qb, kw, kb, vw, vb, qq, kk, vv);
    flash_pam_split<<<1024, 256, 0, stream>>>(qq, kk, vv, O0, O1, lp);
    merge_out<<<1024, 256, 0, stream>>>(O0, O1, lp, x, y, gam, outp);
}